// Round 7
// baseline (2423.725 us; speedup 1.0000x reference)
//
#include <hip/hip_runtime.h>
#include <hip/hip_fp16.h>

// HGNN: 3 layers of e = act(A @ (A^T @ e)), N=150000, E=4.8M, D=64.
// SpMM: pull, 8-way column split (8 cols fp16 = 16B rows, 2.4MB set fits
// per-XCD 4MB L2), packed 4B edges (idx18|val14), nt streams, 4 rows/wave.
// Features carried at scale 2^-8 (pipeline is positively homogeneous; LN is
// scale-invariant with eps*sigma^2) so the final two-hop fits fp16.
// Build: hist -> scan -> LDS-cursor bin (6B) -> per-bucket counting sort (4B CSR).

#define NTOT 150000
#define NE   4800000
#define DD   64
#define NB   147            // buckets of 1024 rows
#define NBLK 512            // build blocks
#define EPB  9375           // edges per build block
#define FSCALE 0.00390625f  // 2^-8 feature scale
#define LN_EPS_S (1e-5f * FSCALE * FSCALE)

typedef unsigned int  u32;
typedef unsigned short u16;
typedef int i4 __attribute__((ext_vector_type(4)));   // native vec for nontemporal builtins

// ---------- phase 1: per-block bucket histogram ----------
__global__ __launch_bounds__(256) void k_hist(const int* __restrict__ rows,
                                              const int* __restrict__ cols,
                                              int* __restrict__ histR,
                                              int* __restrict__ histC) {
    __shared__ int hR[NB], hC[NB];
    const int tid = threadIdx.x, blk = blockIdx.x;
    for (int i = tid; i < NB; i += 256) { hR[i] = 0; hC[i] = 0; }
    __syncthreads();
    const int e0 = blk * EPB;
    const int e1 = min(NE, e0 + EPB);
    for (int e = e0 + tid; e < e1; e += 256) {
        atomicAdd(&hR[rows[e] >> 10], 1);
        atomicAdd(&hC[cols[e] >> 10], 1);
    }
    __syncthreads();
    for (int i = tid; i < NB; i += 256) {
        histR[i * NBLK + blk] = hR[i];
        histC[i * NBLK + blk] = hC[i];
    }
}

// ---------- phase 2: exclusive scan of [bucket][block] + bucket bounds ----------
__global__ __launch_bounds__(1024) void k_scan2(int* __restrict__ hR, int* __restrict__ hC,
                                                int* __restrict__ bbR, int* __restrict__ bbC) {
    __shared__ int wtot[16], wexcl[16];
    __shared__ int ctot;
    int* a  = blockIdx.x ? hC  : hR;
    int* bb = blockIdx.x ? bbC : bbR;
    const int n = NB * NBLK;
    const int tid  = threadIdx.x;
    const int lane = tid & 63, wv = tid >> 6;
    int carry = 0;
    for (int base = 0; base < n; base += 1024) {
        const int i = base + tid;
        const int v = (i < n) ? a[i] : 0;
        int s = v;
        #pragma unroll
        for (int off = 1; off < 64; off <<= 1) {
            int t = __shfl_up(s, off);
            if (lane >= off) s += t;
        }
        if (lane == 63) wtot[wv] = s;
        __syncthreads();
        if (tid == 0) {
            int run = 0;
            #pragma unroll
            for (int w = 0; w < 16; ++w) { wexcl[w] = run; run += wtot[w]; }
            ctot = run;
        }
        __syncthreads();
        if (i < n) a[i] = carry + wexcl[wv] + (s - v);
        carry += ctot;
        __syncthreads();
    }
    for (int i = tid; i <= NB; i += 1024) bb[i] = (i < NB) ? a[i * NBLK] : NE;
}

// ---------- phase 3: bin edges (6B payload), LDS cursors ----------
__global__ __launch_bounds__(256) void k_bin(const int* __restrict__ rows,
                                             const int* __restrict__ cols,
                                             const float* __restrict__ vals,
                                             const int* __restrict__ histR,
                                             const int* __restrict__ histC,
                                             u32* __restrict__ binAR, u16* __restrict__ binQR,
                                             u32* __restrict__ binAC, u16* __restrict__ binQC) {
    __shared__ int cR[NB], cC[NB];
    const int tid = threadIdx.x, blk = blockIdx.x;
    for (int i = tid; i < NB; i += 256) {
        cR[i] = histR[i * NBLK + blk];
        cC[i] = histC[i * NBLK + blk];
    }
    __syncthreads();
    const int e0 = blk * EPB;
    const int e1 = min(NE, e0 + EPB);
    for (int e = e0 + tid; e < e1; e += 256) {
        const int r = rows[e], c = cols[e];
        const u16 q = (u16)(vals[e] * 16383.f + 0.5f);
        int p = atomicAdd(&cR[r >> 10], 1);
        binAR[p] = ((u32)(r & 1023) << 18) | (u32)c;
        binQR[p] = q;
        int p2 = atomicAdd(&cC[c >> 10], 1);
        binAC[p2] = ((u32)(c & 1023) << 18) | (u32)r;
        binQC[p2] = q;
    }
}

// ---------- phase 4: per-bucket counting sort -> packed 4B CSR/CSC + starts ----------
__global__ __launch_bounds__(1024) void k_sort(const int* __restrict__ bbR,
                                               const u32* __restrict__ binAR,
                                               const u16* __restrict__ binQR,
                                               u32* __restrict__ csr, int* __restrict__ startsR,
                                               const int* __restrict__ bbC,
                                               const u32* __restrict__ binAC,
                                               const u16* __restrict__ binQC,
                                               u32* __restrict__ csc, int* __restrict__ startsC) {
    __shared__ int hist[1024];
    __shared__ int cur[1024];
    __shared__ int wtot[16], wexcl[16];
    const int tid = threadIdx.x;
    const int lane = tid & 63, wv = tid >> 6;
    const int dir = (blockIdx.x >= NB) ? 1 : 0;
    const int b = blockIdx.x - dir * NB;
    const int* bb      = dir ? bbC    : bbR;
    const u32* binA    = dir ? binAC  : binAR;
    const u16* binQ    = dir ? binQC  : binQR;
    u32*       out     = dir ? csc    : csr;
    int*       starts  = dir ? startsC : startsR;
    const int ebase = bb[b];
    const int eend  = bb[b + 1];
    hist[tid] = 0;
    __syncthreads();
    for (int i = ebase + tid; i < eend; i += 1024)
        atomicAdd(&hist[binA[i] >> 18], 1);
    __syncthreads();
    const int v = hist[tid];
    int s = v;
    #pragma unroll
    for (int off = 1; off < 64; off <<= 1) { int t = __shfl_up(s, off); if (lane >= off) s += t; }
    if (lane == 63) wtot[wv] = s;
    __syncthreads();
    if (tid == 0) { int run = 0; for (int w = 0; w < 16; ++w) { wexcl[w] = run; run += wtot[w]; } }
    __syncthreads();
    const int excl = ebase + wexcl[wv] + (s - v);
    const int r0 = b << 10;
    if (r0 + tid < NTOT) starts[r0 + tid] = excl;
    cur[tid] = excl;
    __syncthreads();
    for (int i = ebase + tid; i < eend; i += 1024) {
        const u32 a = binA[i];
        const int pos = atomicAdd(&cur[a >> 18], 1);
        out[pos] = ((a & 0x3FFFFu) << 14) | (u32)binQ[i];
    }
    if (blockIdx.x == 0 && tid == 0) { startsR[NTOT] = NE; startsC[NTOT] = NE; }
}

// ---------- ego fp32 -> scaled fp16 eighth layout: [eighth][row][4 half2] ----------
__global__ __launch_bounds__(256) void k_cvt(const float2* __restrict__ x,
                                             __half2* __restrict__ y) {
    int i = blockIdx.x * 256 + threadIdx.x;   // over NTOT*32 half2 slots
    const int r = i >> 5, j = i & 31;          // j = col pair
    const int e8 = j >> 2, slot = j & 3;
    const float2 v = x[i];
    y[(size_t)e8 * (NTOT * 4) + r * 4 + slot] =
        __floats2half2_rn(v.x * FSCALE, v.y * FSCALE);
}

// ---------- eighth pull SpMM: 4 rows/wave x 16 lanes, 1 lane = 1 edge ----------
// MODE 0: plain; MODE 1: LeakyReLU(0.5)
template <int MODE>
__global__ __launch_bounds__(256) void k_spmm8(const int* __restrict__ starts,
                                               const u32* __restrict__ edges,
                                               const int4* __restrict__ x8,
                                               int4* __restrict__ y8) {
    const int w    = (blockIdx.x * 256 + threadIdx.x) >> 6;  // wave id = row group
    const int lane = threadIdx.x & 63;
    const int q = lane >> 4, l = lane & 15;
    const int r = w * 4 + q;                   // 37500*4 = 150000 exactly
    const int s = starts[r];
    const int e = starts[r + 1];
    int m = e - s;
    m = max(m, __shfl_xor(m, 16));
    m = max(m, __shfl_xor(m, 32));
    const int iters = (m + 15) >> 4;
    float a0 = 0.f, a1 = 0.f, a2 = 0.f, a3 = 0.f, a4 = 0.f, a5 = 0.f, a6 = 0.f, a7 = 0.f;
    for (int it = 0; it < iters; ++it) {
        const int idx = s + it * 16 + l;
        if (idx < e) {
            const u32 u = __builtin_nontemporal_load(&edges[idx]);
            const int   c = (int)(u >> 14);
            const float v = (float)(u & 16383u) * (1.f / 16383.f);
            const int4 g = x8[c];
            const __half2* h = (const __half2*)&g;
            float2 f0 = __half22float2(h[0]);
            float2 f1 = __half22float2(h[1]);
            float2 f2 = __half22float2(h[2]);
            float2 f3 = __half22float2(h[3]);
            a0 = fmaf(v, f0.x, a0); a1 = fmaf(v, f0.y, a1);
            a2 = fmaf(v, f1.x, a2); a3 = fmaf(v, f1.y, a3);
            a4 = fmaf(v, f2.x, a4); a5 = fmaf(v, f2.y, a5);
            a6 = fmaf(v, f3.x, a6); a7 = fmaf(v, f3.y, a7);
        }
    }
    #pragma unroll
    for (int off = 1; off < 16; off <<= 1) {
        a0 += __shfl_xor(a0, off); a1 += __shfl_xor(a1, off);
        a2 += __shfl_xor(a2, off); a3 += __shfl_xor(a3, off);
        a4 += __shfl_xor(a4, off); a5 += __shfl_xor(a5, off);
        a6 += __shfl_xor(a6, off); a7 += __shfl_xor(a7, off);
    }
    if (l == 0) {
        if (MODE == 1) {
            a0 = a0 > 0.f ? a0 : 0.5f * a0; a1 = a1 > 0.f ? a1 : 0.5f * a1;
            a2 = a2 > 0.f ? a2 : 0.5f * a2; a3 = a3 > 0.f ? a3 : 0.5f * a3;
            a4 = a4 > 0.f ? a4 : 0.5f * a4; a5 = a5 > 0.f ? a5 : 0.5f * a5;
            a6 = a6 > 0.f ? a6 : 0.5f * a6; a7 = a7 > 0.f ? a7 : 0.5f * a7;
        }
        i4 ov;
        __half2* op = (__half2*)&ov;
        op[0] = __floats2half2_rn(a0, a1);
        op[1] = __floats2half2_rn(a2, a3);
        op[2] = __floats2half2_rn(a4, a5);
        op[3] = __floats2half2_rn(a6, a7);
        __builtin_nontemporal_store(ov, (i4*)&y8[r]);
    }
}

// ---------- LayerNorm + residual from eighth-layout scaled fp16 z ----------
__global__ __launch_bounds__(256) void k_ln2(const int4* __restrict__ z8,
                                             const float* __restrict__ gamma,
                                             const float* __restrict__ beta,
                                             const float* __restrict__ ego,
                                             float* __restrict__ out) {
    const int w    = (blockIdx.x * 256 + threadIdx.x) >> 6;  // wave -> 8 rows
    const int lane = threadIdx.x & 63;
    const int q = lane >> 3, e8 = lane & 7;
    const int r = w * 8 + q;
    if (r >= NTOT) return;
    const int4 g = z8[(size_t)e8 * NTOT + r];
    const __half2* h = (const __half2*)&g;
    float f[8];
    #pragma unroll
    for (int k = 0; k < 4; ++k) {
        const float2 t = __half22float2(h[k]);
        f[2 * k] = t.x; f[2 * k + 1] = t.y;
    }
    float s1 = 0.f;
    #pragma unroll
    for (int k = 0; k < 8; ++k) s1 += f[k];
    #pragma unroll
    for (int off = 1; off < 8; off <<= 1) s1 += __shfl_xor(s1, off);
    const float mu = s1 * (1.f / 64.f);
    float d[8], q2 = 0.f;
    #pragma unroll
    for (int k = 0; k < 8; ++k) { d[k] = f[k] - mu; q2 += d[k] * d[k]; }
    #pragma unroll
    for (int off = 1; off < 8; off <<= 1) q2 += __shfl_xor(q2, off);
    // scale-invariant LN: features carry factor FSCALE, so eps scales by FSCALE^2
    const float rs = rsqrtf(q2 * (1.f / 64.f) + LN_EPS_S);
    const float4* g4 = (const float4*)gamma;
    const float4* b4 = (const float4*)beta;
    const float4* e4 = (const float4*)ego + (size_t)r * 16;
    float4*       o4 = (float4*)out + (size_t)r * 16;
    #pragma unroll
    for (int hh = 0; hh < 2; ++hh) {
        const float4 gg = g4[2 * e8 + hh];
        const float4 bb = b4[2 * e8 + hh];
        const float4 ee = e4[2 * e8 + hh];
        float4 o;
        o.x = d[4 * hh + 0] * rs * gg.x + bb.x + ee.x;
        o.y = d[4 * hh + 1] * rs * gg.y + bb.y + ee.y;
        o.z = d[4 * hh + 2] * rs * gg.z + bb.z + ee.z;
        o.w = d[4 * hh + 3] * rs * gg.w + bb.w + ee.w;
        o4[2 * e8 + hh] = o;
    }
}

// ---------- fallback: atomic push (only if ws too small) ----------
__global__ __launch_bounds__(256) void k_push(const int* __restrict__ src_idx,
                                              const int* __restrict__ dst_idx,
                                              const float* __restrict__ vals,
                                              const float* __restrict__ x,
                                              float* __restrict__ y) {
    int gid  = blockIdx.x * 256 + threadIdx.x;
    int e    = gid >> 6;
    int lane = gid & 63;
    if (e >= NE) return;
    atomicAdd(&y[dst_idx[e] * DD + lane], vals[e] * x[src_idx[e] * DD + lane]);
}

__global__ __launch_bounds__(256) void k_leaky(float* __restrict__ x, int n) {
    int i = blockIdx.x * 256 + threadIdx.x;
    if (i < n) { float v = x[i]; x[i] = v > 0.f ? v : 0.5f * v; }
}

__global__ __launch_bounds__(256) void k_ln(const float* __restrict__ z,
                                            const float* __restrict__ gamma,
                                            const float* __restrict__ beta,
                                            const float* __restrict__ ego,
                                            float* __restrict__ out) {
    int gid  = blockIdx.x * 256 + threadIdx.x;
    int wid  = gid >> 6;
    int lane = threadIdx.x & 63;
    if (wid >= NTOT) return;
    float v = z[wid * DD + lane];
    float sum = v;
    #pragma unroll
    for (int off = 32; off; off >>= 1) sum += __shfl_xor(sum, off);
    float mu = sum * (1.f / 64.f);
    float d  = v - mu;
    float vs = d * d;
    #pragma unroll
    for (int off = 32; off; off >>= 1) vs += __shfl_xor(vs, off);
    float rs = rsqrtf(vs * (1.f / 64.f) + 1e-5f);
    out[wid * DD + lane] = d * rs * gamma[lane] + beta[lane] + ego[wid * DD + lane];
}

extern "C" void kernel_launch(void* const* d_in, const int* in_sizes, int n_in,
                              void* d_out, int out_size, void* d_ws, size_t ws_size,
                              hipStream_t stream) {
    const float* ego   = (const float*)d_in[0];
    const float* vals  = (const float*)d_in[1];
    const float* gamma = (const float*)d_in[2];
    const float* beta  = (const float*)d_in[3];
    const int*   rows  = (const int*)d_in[4];
    const int*   cols  = (const int*)d_in[5];
    float* out = (float*)d_out;

    const size_t SEG4  = (size_t)NE * 4;          // 19,200,000
    const size_t SEG2  = (size_t)NE * 2;          //  9,600,000
    const size_t SMETA = 600064;
    const size_t HSZ   = (size_t)NB * NBLK * 4;   // 301,056
    const size_t NEED  = 5 * SEG4 + 2 * SEG2 + 2 * SMETA + 2 * HSZ + 4096;

    if (ws_size >= NEED) {
        char* w = (char*)d_ws;
        u32* csr   = (u32*)(w);                    // packed CSR (rows dir)
        u32* csc   = (u32*)(w + SEG4);             // packed CSC (cols dir)
        u32* binAR = (u32*)(w + 2 * SEG4);         // -> B1 after sort
        u32* binAC = (u32*)(w + 3 * SEG4);         // -> B2 after sort
        u16* binQR = (u16*)(w + 4 * SEG4);
        u16* binQC = (u16*)(w + 4 * SEG4 + SEG2);
        int* startsR = (int*)(w + 4 * SEG4 + 2 * SEG2);
        int* startsC = (int*)(w + 4 * SEG4 + 2 * SEG2 + SMETA);
        int* histR   = (int*)(w + 4 * SEG4 + 2 * SEG2 + 2 * SMETA);
        int* histC   = (int*)((char*)histR + HSZ);
        int* bbR     = (int*)((char*)histC + HSZ);
        int* bbC     = bbR + (NB + 1);
        // feature eighth-buffers alias dead build scratch
        int4* B1 = (int4*)(w + 2 * SEG4);          // 19.2MB
        int4* B2 = (int4*)(w + 3 * SEG4);          // 19.2MB
        int4* E8 = (int4*)d_out;                   // converted ego (dead before k_ln2)

        k_hist <<<NBLK, 256, 0, stream>>>(rows, cols, histR, histC);
        k_scan2<<<2, 1024, 0, stream>>>(histR, histC, bbR, bbC);
        k_bin  <<<NBLK, 256, 0, stream>>>(rows, cols, vals, histR, histC,
                                          binAR, binQR, binAC, binQC);
        k_sort <<<2 * NB, 1024, 0, stream>>>(bbR, binAR, binQR, csr, startsR,
                                             bbC, binAC, binQC, csc, startsC);
        k_cvt  <<<(NTOT * 32) / 256, 256, 0, stream>>>((const float2*)ego, (__half2*)E8);

        const int GRID_S = (NTOT / 4) * 64 / 256;  // 9375 blocks: wave per 4 rows
        // layer 0: t = A^T e (CSC), z = leaky(A t) (CSR)
        for (int e8 = 0; e8 < 8; ++e8)
            k_spmm8<0><<<GRID_S, 256, 0, stream>>>(startsC, csc, E8 + e8 * NTOT, B1 + e8 * NTOT);
        for (int e8 = 0; e8 < 8; ++e8)
            k_spmm8<1><<<GRID_S, 256, 0, stream>>>(startsR, csr, B1 + e8 * NTOT, B2 + e8 * NTOT);
        // layer 1
        for (int e8 = 0; e8 < 8; ++e8)
            k_spmm8<0><<<GRID_S, 256, 0, stream>>>(startsC, csc, B2 + e8 * NTOT, B1 + e8 * NTOT);
        for (int e8 = 0; e8 < 8; ++e8)
            k_spmm8<1><<<GRID_S, 256, 0, stream>>>(startsR, csr, B1 + e8 * NTOT, B2 + e8 * NTOT);
        // layer 2: t (CSC), z plain (CSR) -> LN + residual
        for (int e8 = 0; e8 < 8; ++e8)
            k_spmm8<0><<<GRID_S, 256, 0, stream>>>(startsC, csc, B2 + e8 * NTOT, B1 + e8 * NTOT);
        for (int e8 = 0; e8 < 8; ++e8)
            k_spmm8<0><<<GRID_S, 256, 0, stream>>>(startsR, csr, B1 + e8 * NTOT, B2 + e8 * NTOT);
        k_ln2<<<(NTOT / 8 + 3) / 4, 256, 0, stream>>>(B2, gamma, beta, ego, out);
    } else {
        const size_t FEAT_BYTES = (size_t)NTOT * DD * 4;
        float* B1 = (float*)d_ws;
        float* B2 = out;
        const int GRID_P = NE / 4;
        const int GRID_N = (NTOT * DD) / 256;
        const float* e = ego;
        for (int layer = 0; layer < 3; ++layer) {
            (void)hipMemsetAsync(B1, 0, FEAT_BYTES, stream);
            k_push<<<GRID_P, 256, 0, stream>>>(rows, cols, vals, e, B1);
            (void)hipMemsetAsync(B2, 0, FEAT_BYTES, stream);
            k_push<<<GRID_P, 256, 0, stream>>>(cols, rows, vals, B1, B2);
            if (layer < 2) {
                k_leaky<<<GRID_N, 256, 0, stream>>>(B2, NTOT * DD);
                e = B2;
            } else {
                k_ln<<<GRID_N, 256, 0, stream>>>(B2, gamma, beta, ego, out);
            }
        }
    }
}